// Round 3
// baseline (198.763 us; speedup 1.0000x reference)
//
#include <hip/hip_runtime.h>
#include <math.h>

#define NW 917

// Ratio tables: offset, rh, rw, cols(=15-rw)
__constant__ int c_off[13]  = {0,121,241,361,442,522,602,651,696,741,789,837,877};
__constant__ int c_rh[13]   = {4,3,5,6,5,7,8,6,10,7,9,7,10};
__constant__ int c_rw[13]   = {4,5,3,6,7,5,8,10,6,9,7,10,7};
__constant__ int c_cols[13] = {11,10,12,9,8,10,7,5,9,6,8,5,8};

__device__ inline void decode_w(int w, int& r, int& i, int& j){
    int rr = 0;
    #pragma unroll
    for (int k = 1; k < 13; ++k) if (w >= c_off[k]) rr = k;
    int loc = w - c_off[rr];
    int cols = c_cols[rr];
    r = rr; i = loc / cols; j = loc - i * cols;
}

// Kernel A: fm_sum[b][196] = sum over 512 channels of local_fm[b][c][14][14]
__global__ __launch_bounds__(512) void chansum_kernel(const float* __restrict__ fm,
                                                      float* __restrict__ fmsum){
    int b = blockIdx.x;
    int t = threadIdx.x;
    int sub = t >> 6, lane = t & 63;   // 8 channel-subgroups x 64 lanes
    __shared__ float4 red[8][49];
    const float4* base = (const float4*)(fm + (size_t)b * 512 * 196);
    if (lane < 49){
        float4 acc = {0.f,0.f,0.f,0.f};
        int c0 = sub * 64;
        #pragma unroll 8
        for (int c = 0; c < 64; ++c){
            float4 v = base[(size_t)(c0 + c) * 49 + lane];
            acc.x += v.x; acc.y += v.y; acc.z += v.z; acc.w += v.w;
        }
        red[sub][lane] = acc;
    }
    __syncthreads();
    if (t < 49){
        float4 s = red[0][t];
        #pragma unroll
        for (int k = 1; k < 8; ++k){
            float4 v = red[k][t];
            s.x += v.x; s.y += v.y; s.z += v.z; s.w += v.w;
        }
        ((float4*)fmsum)[b * 49 + t] = s;
    }
}

// Kernel B: per-b: integral image -> 917 window scores -> greedy NMS per group
__global__ __launch_bounds__(256) void appm_kernel(const float* __restrict__ fmsum,
                                                   float* __restrict__ out_scores,
                                                   float* __restrict__ out_idx,
                                                   float* __restrict__ out_psc){
    int b = blockIdx.x, t = threadIdx.x;
    __shared__ float fm[196];
    __shared__ float R[14][15];   // row prefix, R[i][0]=0
    __shared__ float I[15][15];   // exclusive 2D integral
    __shared__ float s[NW];
    __shared__ float rv[256];
    __shared__ int   ri[256];

    if (t < 196) fm[t] = fmsum[b * 196 + t];
    __syncthreads();
    if (t < 14){
        float run = 0.f;
        R[t][0] = 0.f;
        for (int j = 0; j < 14; ++j){ run += fm[t * 14 + j]; R[t][j + 1] = run; }
    }
    __syncthreads();
    if (t < 15){
        float run = 0.f;
        I[0][t] = 0.f;
        for (int i = 0; i < 14; ++i){ run += R[i][t]; I[i + 1][t] = run; }
    }
    __syncthreads();
    for (int w = t; w < NW; w += 256){
        int r, i, j; decode_w(w, r, i, j);
        int rh = c_rh[r], rw = c_rw[r];
        float sum = I[i + rh][j + rw] - I[i][j + rw] - I[i + rh][j] + I[i][j];
        float sc = sum / (float)(rh * rw);
        s[w] = sc;
        out_scores[(size_t)b * NW + w] = sc;
    }
    __syncthreads();

    const int gs_[3] = {0, 361, 602};
    const int ge_[3] = {361, 602, NW};
    const int np_[3] = {3, 2, 1};
    int slot = 0;
    for (int g = 0; g < 3; ++g){
        int gs = gs_[g], ge = ge_[g];
        int w0 = gs + t, w1 = gs + t + 256;
        bool has0 = w0 < ge, has1 = w1 < ge;
        float x00=0,y00=0,x10=0,y10=0,a0=1.f;
        float x01=0,y01=0,x11=0,y11=0,a1=1.f;
        if (has0){
            int r,i,j; decode_w(w0,r,i,j);
            x00 = i*32.f; y00 = j*32.f;
            x10 = x00 + c_rh[r]*32.f - 1.f; y10 = y00 + c_rw[r]*32.f - 1.f;
            a0  = (float)(c_rh[r]*32 * c_rw[r]*32);
        }
        if (has1){
            int r,i,j; decode_w(w1,r,i,j);
            x01 = i*32.f; y01 = j*32.f;
            x11 = x01 + c_rh[r]*32.f - 1.f; y11 = y01 + c_rw[r]*32.f - 1.f;
            a1  = (float)(c_rh[r]*32 * c_rw[r]*32);
        }
        bool v0 = true, v1 = true;
        int last = 0;
        for (int p = 0; p < np_[g]; ++p){
            float bv = -INFINITY; int bi = 0x7fffffff;
            if (has0 && v0){ bv = s[w0]; bi = w0; }
            if (has1 && v1){ float sv = s[w1]; if (sv > bv){ bv = sv; bi = w1; } }
            rv[t] = bv; ri[t] = bi;
            __syncthreads();
            for (int st = 128; st > 0; st >>= 1){
                if (t < st){
                    float ov = rv[t + st]; int oi = ri[t + st];
                    if (ov > rv[t] || (ov == rv[t] && oi < ri[t])){ rv[t] = ov; ri[t] = oi; }
                }
                __syncthreads();
            }
            float mv = rv[0];
            int pick = (mv == -INFINITY) ? last : ri[0];
            __syncthreads();   // rv/ri reused next iteration
            last = pick;
            int pr, pi, pj; decode_w(pick, pr, pi, pj);
            float px0 = pi*32.f, py0 = pj*32.f;
            float px1 = px0 + c_rh[pr]*32.f - 1.f, py1 = py0 + c_rw[pr]*32.f - 1.f;
            float pa  = (float)(c_rh[pr]*32 * c_rw[pr]*32);
            if (has0 && v0){
                float lx = fminf(x10,px1) - fmaxf(x00,px0) + 1.f;
                float ly = fminf(y10,py1) - fmaxf(y00,py0) + 1.f;
                float inter = (lx < 0.f || ly < 0.f) ? 0.f : lx * ly;
                float iou = inter / (a0 + pa - inter);
                v0 = (iou <= 0.25f);
            }
            if (has1 && v1){
                float lx = fminf(x11,px1) - fmaxf(x01,px0) + 1.f;
                float ly = fminf(y11,py1) - fmaxf(y01,py0) + 1.f;
                float inter = (lx < 0.f || ly < 0.f) ? 0.f : lx * ly;
                float iou = inter / (a1 + pa - inter);
                v1 = (iou <= 0.25f);
            }
            if (t == 0){
                out_idx[b * 6 + slot] = (float)pick;
                out_psc[b * 6 + slot] = s[pick];
            }
            slot++;
        }
    }
}

// Kernel C: logits -> argmax mask -> hash
__global__ __launch_bounds__(256) void cls_kernel(const float* __restrict__ E,
                                                  const float* __restrict__ Wc,
                                                  const float* __restrict__ bc,
                                                  const float* __restrict__ Wh,
                                                  const float* __restrict__ bh,
                                                  float* __restrict__ out_hash,
                                                  float* __restrict__ out_logits){
    int b = blockIdx.x, t = threadIdx.x;
    __shared__ float emb[512];
    __shared__ float lg[200];
    __shared__ float mk[200];
    __shared__ float rv[256];
    __shared__ int   ri[256];
    emb[t]       = E[b * 512 + t];
    emb[t + 256] = E[b * 512 + 256 + t];
    __syncthreads();
    float lv = -INFINITY;
    if (t < 200){
        const float4* w4 = (const float4*)(Wc + (size_t)t * 512);
        float acc = bc[t];
        #pragma unroll 16
        for (int k = 0; k < 128; ++k){
            float4 w = w4[k];
            acc += emb[4*k]*w.x + emb[4*k+1]*w.y + emb[4*k+2]*w.z + emb[4*k+3]*w.w;
        }
        lg[t] = acc;
        out_logits[(size_t)b * 200 + t] = acc;
        lv = acc;
    }
    rv[t] = lv; ri[t] = t;
    __syncthreads();
    for (int st = 128; st > 0; st >>= 1){
        if (t < st){
            float ov = rv[t + st]; int oi = ri[t + st];
            if (ov > rv[t] || (ov == rv[t] && oi < ri[t])){ rv[t] = ov; ri[t] = oi; }
        }
        __syncthreads();
    }
    int amax = ri[0];
    if (t < 200) mk[t] = lg[t] * (t == amax ? 1.0f : 0.7f);
    __syncthreads();
    if (t < 48){
        const float4* w4 = (const float4*)(Wh + (size_t)t * 200);
        float acc = bh[t];
        #pragma unroll
        for (int k = 0; k < 50; ++k){
            float4 w = w4[k];
            acc += mk[4*k]*w.x + mk[4*k+1]*w.y + mk[4*k+2]*w.z + mk[4*k+3]*w.w;
        }
        out_hash[b * 48 + t] = tanhf(acc);
    }
}

extern "C" void kernel_launch(void* const* d_in, const int* in_sizes, int n_in,
                              void* d_out, int out_size, void* d_ws, size_t ws_size,
                              hipStream_t stream) {
    const float* fm = (const float*)d_in[0];
    const float* E  = (const float*)d_in[1];
    const float* Wc = (const float*)d_in[2];
    const float* bc = (const float*)d_in[3];
    const float* Wh = (const float*)d_in[4];
    const float* bh = (const float*)d_in[5];
    float* out        = (float*)d_out;
    float* out_hash   = out;                 // 256*48   = 12288
    float* out_logits = out + 12288;         // 256*200  = 51200
    float* out_idx    = out + 63488;         // 256*6    = 1536
    float* out_psc    = out + 65024;         // 256*6    = 1536
    float* out_scores = out + 66560;         // 256*917  = 234752
    float* fmsum = (float*)d_ws;             // 256*196 floats

    hipLaunchKernelGGL(chansum_kernel, dim3(256), dim3(512), 0, stream, fm, fmsum);
    hipLaunchKernelGGL(appm_kernel,    dim3(256), dim3(256), 0, stream, fmsum,
                       out_scores, out_idx, out_psc);
    hipLaunchKernelGGL(cls_kernel,     dim3(256), dim3(256), 0, stream, E, Wc, bc, Wh, bh,
                       out_hash, out_logits);
}

// Round 4
// 187.309 us; speedup vs baseline: 1.0612x; 1.0612x over previous
//
#include <hip/hip_runtime.h>
#include <math.h>

#define NW 917

// Ratio tables: offset, rh, rw, cols(=15-rw)
__constant__ int c_off[13]  = {0,121,241,361,442,522,602,651,696,741,789,837,877};
__constant__ int c_rh[13]   = {4,3,5,6,5,7,8,6,10,7,9,7,10};
__constant__ int c_rw[13]   = {4,5,3,6,7,5,8,10,6,9,7,10,7};
__constant__ int c_cols[13] = {11,10,12,9,8,10,7,5,9,6,8,5,8};

__device__ inline void decode_w(int w, int& r, int& i, int& j){
    int rr = 0;
    #pragma unroll
    for (int k = 1; k < 13; ++k) if (w >= c_off[k]) rr = k;
    int loc = w - c_off[rr];
    int cols = c_cols[rr];
    r = rr; i = loc / cols; j = loc - i * cols;
}

// Monotonic float -> uint; key = (mono << 32) | (0xFFFFFFFF - idx)
// max(key) == (max value, first index on ties). key==0 <=> no candidate.
__device__ inline unsigned long long nms_key(float v, int w){
    unsigned u = __float_as_uint(v);
    u = (u & 0x80000000u) ? ~u : (u | 0x80000000u);
    return ((unsigned long long)u << 32) | (unsigned)(0xFFFFFFFFu - (unsigned)w);
}

__device__ inline unsigned long long shfl_xor_u64(unsigned long long x, int m){
    unsigned lo = (unsigned)x, hi = (unsigned)(x >> 32);
    lo = __shfl_xor(lo, m);
    hi = __shfl_xor(hi, m);
    return ((unsigned long long)hi << 32) | lo;
}

// Fused kernel 1:
//  blocks [0,1024):   chansum partial — block (b, part) sums channels part*128..+127
//  blocks [1024,1280): cls path for b = blockIdx.x - 1024
__global__ __launch_bounds__(256) void fused1_kernel(const float* __restrict__ fm,
                                                     const float* __restrict__ E,
                                                     const float* __restrict__ Wc,
                                                     const float* __restrict__ bc,
                                                     const float* __restrict__ Wh,
                                                     const float* __restrict__ bh,
                                                     float* __restrict__ partial,
                                                     float* __restrict__ out_hash,
                                                     float* __restrict__ out_logits){
    int t = threadIdx.x;
    int lane = t & 63, wv = t >> 6;
    if (blockIdx.x < 1024){
        int b = blockIdx.x >> 2, part = blockIdx.x & 3;
        __shared__ float4 red[4][49];
        const float4* base = (const float4*)(fm + (size_t)b * 512 * 196)
                             + (size_t)(part * 128) * 49;
        if (lane < 49){
            float4 acc = {0.f,0.f,0.f,0.f};
            int c0 = wv * 32;
            #pragma unroll 8
            for (int k = 0; k < 32; ++k){
                float4 v = base[(size_t)(c0 + k) * 49 + lane];
                acc.x += v.x; acc.y += v.y; acc.z += v.z; acc.w += v.w;
            }
            red[wv][lane] = acc;
        }
        __syncthreads();
        if (t < 49){
            float4 s0 = red[0][t], s1 = red[1][t], s2 = red[2][t], s3 = red[3][t];
            float4 s;
            s.x = (s0.x + s1.x) + (s2.x + s3.x);
            s.y = (s0.y + s1.y) + (s2.y + s3.y);
            s.z = (s0.z + s1.z) + (s2.z + s3.z);
            s.w = (s0.w + s1.w) + (s2.w + s3.w);
            ((float4*)partial)[(blockIdx.x) * 49 + t] = s;
        }
    } else {
        int b = blockIdx.x - 1024;
        __shared__ float emb[512];
        __shared__ float lg[200];
        __shared__ float mk[200];
        __shared__ unsigned long long wredc[4];
        emb[t]       = E[b * 512 + t];
        emb[t + 256] = E[b * 512 + 256 + t];
        __syncthreads();
        float lv = 0.f;
        if (t < 200){
            const float4* w4 = (const float4*)(Wc + (size_t)t * 512);
            float acc = bc[t];
            #pragma unroll 16
            for (int k = 0; k < 128; ++k){
                float4 w = w4[k];
                acc += emb[4*k]*w.x + emb[4*k+1]*w.y + emb[4*k+2]*w.z + emb[4*k+3]*w.w;
            }
            lg[t] = acc;
            out_logits[(size_t)b * 200 + t] = acc;
            lv = acc;
        }
        unsigned long long key = (t < 200) ? nms_key(lv, t) : 0ULL;
        #pragma unroll
        for (int off = 32; off > 0; off >>= 1){
            unsigned long long o = shfl_xor_u64(key, off);
            if (o > key) key = o;
        }
        if (lane == 0) wredc[wv] = key;
        __syncthreads();   // covers lg[] writes too
        unsigned long long ka = wredc[0] > wredc[1] ? wredc[0] : wredc[1];
        unsigned long long kb = wredc[2] > wredc[3] ? wredc[2] : wredc[3];
        if (kb > ka) ka = kb;
        int amax = (int)(0xFFFFFFFFu - (unsigned)(ka & 0xFFFFFFFFu));
        if (t < 200) mk[t] = lg[t] * (t == amax ? 1.0f : 0.7f);
        __syncthreads();
        if (t < 48){
            const float4* w4 = (const float4*)(Wh + (size_t)t * 200);
            float acc = bh[t];
            #pragma unroll
            for (int k = 0; k < 50; ++k){
                float4 w = w4[k];
                acc += mk[4*k]*w.x + mk[4*k+1]*w.y + mk[4*k+2]*w.z + mk[4*k+3]*w.w;
            }
            out_hash[b * 48 + t] = tanhf(acc);
        }
    }
}

// Kernel 2: per-b: sum 4 partials -> integral image -> 917 scores -> greedy NMS
__global__ __launch_bounds__(256) void appm_kernel(const float* __restrict__ partial,
                                                   float* __restrict__ out_scores,
                                                   float* __restrict__ out_idx,
                                                   float* __restrict__ out_psc){
    int b = blockIdx.x, t = threadIdx.x;
    int lane = t & 63, wv = t >> 6;
    __shared__ float fm[196];
    __shared__ float R[14][15];   // row prefix, R[i][0]=0
    __shared__ float I[15][15];   // exclusive 2D integral
    __shared__ float s[NW];
    __shared__ unsigned long long wred[4];

    if (t < 196){
        const float* p = partial + (size_t)b * 784 + t;
        fm[t] = (p[0] + p[196]) + (p[392] + p[588]);
    }
    __syncthreads();
    if (t < 14){
        float run = 0.f;
        R[t][0] = 0.f;
        for (int j = 0; j < 14; ++j){ run += fm[t * 14 + j]; R[t][j + 1] = run; }
    }
    __syncthreads();
    if (t < 15){
        float run = 0.f;
        I[0][t] = 0.f;
        for (int i = 0; i < 14; ++i){ run += R[i][t]; I[i + 1][t] = run; }
    }
    __syncthreads();
    for (int w = t; w < NW; w += 256){
        int r, i, j; decode_w(w, r, i, j);
        int rh = c_rh[r], rw = c_rw[r];
        float sum = I[i + rh][j + rw] - I[i][j + rw] - I[i + rh][j] + I[i][j];
        float sc = sum / (float)(rh * rw);
        s[w] = sc;
        out_scores[(size_t)b * NW + w] = sc;
    }
    __syncthreads();

    const int gs_[3] = {0, 361, 602};
    const int ge_[3] = {361, 602, NW};
    const int np_[3] = {3, 2, 1};
    int slot = 0;
    for (int g = 0; g < 3; ++g){
        int gs = gs_[g], ge = ge_[g];
        int w0 = gs + t, w1 = gs + t + 256;
        bool has0 = w0 < ge, has1 = w1 < ge;
        float x00=0,y00=0,x10=0,y10=0,a0=1.f;
        float x01=0,y01=0,x11=0,y11=0,a1=1.f;
        if (has0){
            int r,i,j; decode_w(w0,r,i,j);
            x00 = i*32.f; y00 = j*32.f;
            x10 = x00 + c_rh[r]*32.f - 1.f; y10 = y00 + c_rw[r]*32.f - 1.f;
            a0  = (float)(c_rh[r]*32 * c_rw[r]*32);
        }
        if (has1){
            int r,i,j; decode_w(w1,r,i,j);
            x01 = i*32.f; y01 = j*32.f;
            x11 = x01 + c_rh[r]*32.f - 1.f; y11 = y01 + c_rw[r]*32.f - 1.f;
            a1  = (float)(c_rh[r]*32 * c_rw[r]*32);
        }
        bool v0 = true, v1 = true;
        int last = 0;
        for (int p = 0; p < np_[g]; ++p){
            unsigned long long key = 0ULL;
            if (has0 && v0) key = nms_key(s[w0], w0);
            if (has1 && v1){
                unsigned long long k2 = nms_key(s[w1], w1);
                if (k2 > key) key = k2;
            }
            #pragma unroll
            for (int off = 32; off > 0; off >>= 1){
                unsigned long long o = shfl_xor_u64(key, off);
                if (o > key) key = o;
            }
            if (lane == 0) wred[wv] = key;
            __syncthreads();
            unsigned long long ka = wred[0] > wred[1] ? wred[0] : wred[1];
            unsigned long long kb = wred[2] > wred[3] ? wred[2] : wred[3];
            if (kb > ka) ka = kb;
            int pick = (ka == 0ULL) ? last
                                    : (int)(0xFFFFFFFFu - (unsigned)(ka & 0xFFFFFFFFu));
            __syncthreads();   // wred reused next pick
            last = pick;
            int pr, pi, pj; decode_w(pick, pr, pi, pj);
            float px0 = pi*32.f, py0 = pj*32.f;
            float px1 = px0 + c_rh[pr]*32.f - 1.f, py1 = py0 + c_rw[pr]*32.f - 1.f;
            float pa  = (float)(c_rh[pr]*32 * c_rw[pr]*32);
            if (has0 && v0){
                float lx = fminf(x10,px1) - fmaxf(x00,px0) + 1.f;
                float ly = fminf(y10,py1) - fmaxf(y00,py0) + 1.f;
                float inter = (lx < 0.f || ly < 0.f) ? 0.f : lx * ly;
                float iou = inter / (a0 + pa - inter);
                v0 = (iou <= 0.25f);
            }
            if (has1 && v1){
                float lx = fminf(x11,px1) - fmaxf(x01,px0) + 1.f;
                float ly = fminf(y11,py1) - fmaxf(y01,py0) + 1.f;
                float inter = (lx < 0.f || ly < 0.f) ? 0.f : lx * ly;
                float iou = inter / (a1 + pa - inter);
                v1 = (iou <= 0.25f);
            }
            if (t == 0){
                out_idx[b * 6 + slot] = (float)pick;
                out_psc[b * 6 + slot] = s[pick];
            }
            slot++;
        }
    }
}

extern "C" void kernel_launch(void* const* d_in, const int* in_sizes, int n_in,
                              void* d_out, int out_size, void* d_ws, size_t ws_size,
                              hipStream_t stream) {
    const float* fm = (const float*)d_in[0];
    const float* E  = (const float*)d_in[1];
    const float* Wc = (const float*)d_in[2];
    const float* bc = (const float*)d_in[3];
    const float* Wh = (const float*)d_in[4];
    const float* bh = (const float*)d_in[5];
    float* out        = (float*)d_out;
    float* out_hash   = out;                 // 256*48   = 12288
    float* out_logits = out + 12288;         // 256*200  = 51200
    float* out_idx    = out + 63488;         // 256*6    = 1536
    float* out_psc    = out + 65024;         // 256*6    = 1536
    float* out_scores = out + 66560;         // 256*917  = 234752
    float* partial    = (float*)d_ws;        // 256*4*196 floats = 802816 B

    hipLaunchKernelGGL(fused1_kernel, dim3(1280), dim3(256), 0, stream,
                       fm, E, Wc, bc, Wh, bh, partial, out_hash, out_logits);
    hipLaunchKernelGGL(appm_kernel,   dim3(256),  dim3(256), 0, stream,
                       partial, out_scores, out_idx, out_psc);
}

// Round 6
// 179.958 us; speedup vs baseline: 1.1045x; 1.0408x over previous
//
#include <hip/hip_runtime.h>
#include <math.h>

#define NW 917

// Ratio tables: offset, rh, rw, cols(=15-rw)
__constant__ int c_off[13]  = {0,121,241,361,442,522,602,651,696,741,789,837,877};
__constant__ int c_rh[13]   = {4,3,5,6,5,7,8,6,10,7,9,7,10};
__constant__ int c_rw[13]   = {4,5,3,6,7,5,8,10,6,9,7,10,7};
__constant__ int c_cols[13] = {11,10,12,9,8,10,7,5,9,6,8,5,8};

__device__ inline void decode_w(int w, int& r, int& i, int& j){
    int rr = 0;
    #pragma unroll
    for (int k = 1; k < 13; ++k) if (w >= c_off[k]) rr = k;
    int loc = w - c_off[rr];
    int cols = c_cols[rr];
    r = rr; i = loc / cols; j = loc - i * cols;
}

// Monotonic float -> uint; key = (mono << 32) | (0xFFFFFFFF - idx)
// max(key) == (max value, first index on ties). key==0 <=> no candidate.
__device__ inline unsigned long long nms_key(float v, int w){
    unsigned u = __float_as_uint(v);
    u = (u & 0x80000000u) ? ~u : (u | 0x80000000u);
    return ((unsigned long long)u << 32) | (unsigned)(0xFFFFFFFFu - (unsigned)w);
}

__device__ inline unsigned long long shfl_xor_u64(unsigned long long x, int m){
    unsigned lo = (unsigned)x, hi = (unsigned)(x >> 32);
    lo = __shfl_xor(lo, m);
    hi = __shfl_xor(hi, m);
    return ((unsigned long long)hi << 32) | lo;
}

// One block per batch row: chansum -> integral -> scores -> NMS -> cls.
__global__ __launch_bounds__(1024) void mono_kernel(const float* __restrict__ fm,
                                                    const float* __restrict__ E,
                                                    const float* __restrict__ Wc,
                                                    const float* __restrict__ bc,
                                                    const float* __restrict__ Wh,
                                                    const float* __restrict__ bh,
                                                    float* __restrict__ out_hash,
                                                    float* __restrict__ out_logits,
                                                    float* __restrict__ out_idx,
                                                    float* __restrict__ out_psc,
                                                    float* __restrict__ out_scores){
    int b = blockIdx.x, t = threadIdx.x;
    int lane = t & 63, wv = t >> 6;     // 16 waves

    __shared__ float4 red[16][49];
    __shared__ float fmS[196];
    __shared__ float R[14][15];         // row prefix, R[i][0]=0
    __shared__ float I[15][15];         // exclusive 2D integral
    __shared__ float s[NW];
    __shared__ unsigned long long wred[16];
    __shared__ float emb[512];
    __shared__ float lg[200];
    __shared__ float mk[200];

    // ---- phase 1: channel sum over 512 channels (each wave owns 32) ----
    const float4* base = (const float4*)(fm + (size_t)b * 512 * 196);
    if (lane < 49){
        float4 acc = {0.f,0.f,0.f,0.f};
        int c0 = wv * 32;
        #pragma unroll 8
        for (int k = 0; k < 32; ++k){
            float4 v = base[(size_t)(c0 + k) * 49 + lane];
            acc.x += v.x; acc.y += v.y; acc.z += v.z; acc.w += v.w;
        }
        red[wv][lane] = acc;
    }
    if (t < 512) emb[t] = E[b * 512 + t];   // overlap with chansum drain
    __syncthreads();
    if (t < 49){
        float4 a = red[0][t];
        #pragma unroll
        for (int k = 1; k < 16; ++k){
            float4 v = red[k][t];
            a.x += v.x; a.y += v.y; a.z += v.z; a.w += v.w;
        }
        ((float4*)fmS)[t] = a;
    }
    __syncthreads();

    // ---- phase 2: integral image ----
    if (t < 14){
        float run = 0.f;
        R[t][0] = 0.f;
        for (int j = 0; j < 14; ++j){ run += fmS[t * 14 + j]; R[t][j + 1] = run; }
    }
    __syncthreads();
    if (t < 15){
        float run = 0.f;
        I[0][t] = 0.f;
        for (int i = 0; i < 14; ++i){ run += R[i][t]; I[i + 1][t] = run; }
    }
    __syncthreads();

    // ---- phase 3: 917 window scores ----
    if (t < NW){
        int r, i, j; decode_w(t, r, i, j);
        int rh = c_rh[r], rw = c_rw[r];
        float sum = I[i + rh][j + rw] - I[i][j + rw] - I[i + rh][j] + I[i][j];
        float sc = sum / (float)(rh * rw);
        s[t] = sc;
        out_scores[(size_t)b * NW + t] = sc;
    }
    __syncthreads();

    // ---- phase 4: greedy NMS per group (1 candidate per thread) ----
    const int gs_[3] = {0, 361, 602};
    const int ge_[3] = {361, 602, NW};
    const int np_[3] = {3, 2, 1};
    int slot = 0;
    for (int g = 0; g < 3; ++g){
        int gs = gs_[g], m = ge_[g] - gs;
        bool has = t < m;
        int w0 = gs + t;
        float x0=0,y0=0,x1=0,y1=0,ar=1.f,sc=0.f;
        if (has){
            int r,i,j; decode_w(w0,r,i,j);
            x0 = i*32.f; y0 = j*32.f;
            x1 = x0 + c_rh[r]*32.f - 1.f; y1 = y0 + c_rw[r]*32.f - 1.f;
            ar = (float)(c_rh[r]*32 * c_rw[r]*32);
            sc = s[w0];
        }
        bool v = true;
        int last = 0;
        for (int p = 0; p < np_[g]; ++p){
            unsigned long long key = (has && v) ? nms_key(sc, w0) : 0ULL;
            #pragma unroll
            for (int off = 32; off > 0; off >>= 1){
                unsigned long long o = shfl_xor_u64(key, off);
                if (o > key) key = o;
            }
            if (lane == 0) wred[wv] = key;
            __syncthreads();
            unsigned long long best = wred[0];
            #pragma unroll
            for (int k = 1; k < 16; ++k) if (wred[k] > best) best = wred[k];
            int pick = (best == 0ULL) ? last
                                      : (int)(0xFFFFFFFFu - (unsigned)(best & 0xFFFFFFFFu));
            last = pick;
            int pr, pi, pj; decode_w(pick, pr, pi, pj);
            float px0 = pi*32.f, py0 = pj*32.f;
            float px1 = px0 + c_rh[pr]*32.f - 1.f, py1 = py0 + c_rw[pr]*32.f - 1.f;
            float pa  = (float)(c_rh[pr]*32 * c_rw[pr]*32);
            if (has && v){
                float lx = fminf(x1,px1) - fmaxf(x0,px0) + 1.f;
                float ly = fminf(y1,py1) - fmaxf(y0,py0) + 1.f;
                float inter = (lx < 0.f || ly < 0.f) ? 0.f : lx * ly;
                float iou = inter / (ar + pa - inter);
                v = (iou <= 0.25f);
            }
            if (t == 0){
                out_idx[b * 6 + slot] = (float)pick;
                out_psc[b * 6 + slot] = s[pick];
            }
            slot++;
            __syncthreads();   // wred reused next pick
        }
    }

    // ---- phase 5: cls (2 threads per class row) ----
    float tot = 0.f;
    if (t < 400){
        int row = t >> 1, part = t & 1;
        const float4* w4 = (const float4*)(Wc + (size_t)row * 512) + part * 64;
        const float* e = emb + part * 256;
        float acc = (part == 0) ? bc[row] : 0.f;
        #pragma unroll 8
        for (int k = 0; k < 64; ++k){
            float4 w = w4[k];
            acc += e[4*k]*w.x + e[4*k+1]*w.y + e[4*k+2]*w.z + e[4*k+3]*w.w;
        }
        tot = acc + __shfl_xor(acc, 1);
        if (part == 0){
            lg[row] = tot;
            out_logits[(size_t)b * 200 + row] = tot;
        }
    }
    unsigned long long key = (t < 400 && !(t & 1)) ? nms_key(tot, t >> 1) : 0ULL;
    #pragma unroll
    for (int off = 32; off > 0; off >>= 1){
        unsigned long long o = shfl_xor_u64(key, off);
        if (o > key) key = o;
    }
    if (lane == 0) wred[wv] = key;
    __syncthreads();
    unsigned long long best = wred[0];
    #pragma unroll
    for (int k = 1; k < 16; ++k) if (wred[k] > best) best = wred[k];
    int amax = (int)(0xFFFFFFFFu - (unsigned)(best & 0xFFFFFFFFu));
    if (t < 200) mk[t] = lg[t] * (t == amax ? 1.0f : 0.7f);
    __syncthreads();
    if (t < 96){
        int row = t >> 1, part = t & 1;
        const float4* w4 = (const float4*)(Wh + (size_t)row * 200) + part * 25;
        const float* mm = mk + part * 100;
        float acc = (part == 0) ? bh[row] : 0.f;
        #pragma unroll
        for (int k = 0; k < 25; ++k){
            float4 w = w4[k];
            acc += mm[4*k]*w.x + mm[4*k+1]*w.y + mm[4*k+2]*w.z + mm[4*k+3]*w.w;
        }
        float tt = acc + __shfl_xor(acc, 1);
        if (part == 0) out_hash[b * 48 + row] = tanhf(tt);
    }
}

extern "C" void kernel_launch(void* const* d_in, const int* in_sizes, int n_in,
                              void* d_out, int out_size, void* d_ws, size_t ws_size,
                              hipStream_t stream) {
    const float* fm = (const float*)d_in[0];
    const float* E  = (const float*)d_in[1];
    const float* Wc = (const float*)d_in[2];
    const float* bc = (const float*)d_in[3];
    const float* Wh = (const float*)d_in[4];
    const float* bh = (const float*)d_in[5];
    float* out        = (float*)d_out;
    float* out_hash   = out;                 // 256*48   = 12288
    float* out_logits = out + 12288;         // 256*200  = 51200
    float* out_idx    = out + 63488;         // 256*6    = 1536
    float* out_psc    = out + 65024;         // 256*6    = 1536
    float* out_scores = out + 66560;         // 256*917  = 234752

    hipLaunchKernelGGL(mono_kernel, dim3(256), dim3(1024), 0, stream,
                       fm, E, Wc, bc, Wh, bh,
                       out_hash, out_logits, out_idx, out_psc, out_scores);
}

// Round 7
// 169.981 us; speedup vs baseline: 1.1693x; 1.0587x over previous
//
#include <hip/hip_runtime.h>
#include <math.h>

#define NW 917

// Ratio tables: offset, rh, rw, cols(=15-rw)
__constant__ int c_off[13]  = {0,121,241,361,442,522,602,651,696,741,789,837,877};
__constant__ int c_rh[13]   = {4,3,5,6,5,7,8,6,10,7,9,7,10};
__constant__ int c_rw[13]   = {4,5,3,6,7,5,8,10,6,9,7,10,7};
__constant__ int c_cols[13] = {11,10,12,9,8,10,7,5,9,6,8,5,8};

__device__ inline void decode_w(int w, int& r, int& i, int& j){
    int rr = 0;
    #pragma unroll
    for (int k = 1; k < 13; ++k) if (w >= c_off[k]) rr = k;
    int loc = w - c_off[rr];
    int cols = c_cols[rr];
    r = rr; i = loc / cols; j = loc - i * cols;
}

// Monotonic float -> uint; key = (mono << 32) | (0xFFFFFFFF - idx)
// max(key) == (max value, first index on ties). key==0 <=> no candidate.
__device__ inline unsigned long long nms_key(float v, int w){
    unsigned u = __float_as_uint(v);
    u = (u & 0x80000000u) ? ~u : (u | 0x80000000u);
    return ((unsigned long long)u << 32) | (unsigned)(0xFFFFFFFFu - (unsigned)w);
}

__device__ inline unsigned long long shfl_xor_u64(unsigned long long x, int m){
    unsigned lo = (unsigned)x, hi = (unsigned)(x >> 32);
    lo = __shfl_xor(lo, m);
    hi = __shfl_xor(hi, m);
    return ((unsigned long long)hi << 32) | lo;
}

// One block per batch row.
__global__ __launch_bounds__(1024) void mono_kernel(const float* __restrict__ fm,
                                                    const float* __restrict__ E,
                                                    const float* __restrict__ Wc,
                                                    const float* __restrict__ bc,
                                                    const float* __restrict__ Wh,
                                                    const float* __restrict__ bh,
                                                    float* __restrict__ out_hash,
                                                    float* __restrict__ out_logits,
                                                    float* __restrict__ out_idx,
                                                    float* __restrict__ out_psc,
                                                    float* __restrict__ out_scores){
    int b = blockIdx.x, t = threadIdx.x;
    int lane = t & 63, wv = t >> 6;     // 16 waves

    __shared__ float4 red[20][49];      // chansum partials (cg-major)
    __shared__ float fmS[196];
    __shared__ float R[14][15];         // row prefix, R[i][0]=0
    __shared__ float I[15][15];         // exclusive 2D integral
    __shared__ float s[NW];
    __shared__ float emb[512];
    __shared__ float lg[200];
    __shared__ float mk[200];

    // ---- phase 1: channel sum, flat coalesced. float4 idx = c*49 + pos.
    // thread t<980: pos=t%49, cg=t/49; channels c = cg + 20k -> addr = base + t + 980k.
    const float4* base = (const float4*)(fm + (size_t)b * 512 * 196);
    if (t < 980){
        int cg = t / 49;
        const float4* p4 = base + t;
        float4 acc = {0.f,0.f,0.f,0.f};
        #pragma unroll 5
        for (int k = 0; k < 25; ++k){
            float4 v = p4[980 * k];
            acc.x += v.x; acc.y += v.y; acc.z += v.z; acc.w += v.w;
        }
        if (cg < 12){               // channels 500..511
            float4 v = p4[980 * 25];
            acc.x += v.x; acc.y += v.y; acc.z += v.z; acc.w += v.w;
        }
        red[cg][t - cg * 49] = acc;
    }
    if (t < 512) emb[t] = E[b * 512 + t];   // overlap with chansum
    __syncthreads();
    if (t < 49){
        float4 a = red[0][t];
        #pragma unroll
        for (int k = 1; k < 20; ++k){
            float4 v = red[k][t];
            a.x += v.x; a.y += v.y; a.z += v.z; a.w += v.w;
        }
        ((float4*)fmS)[t] = a;
    }
    __syncthreads();

    // ---- phase 2: integral image ----
    if (t < 14){
        float run = 0.f;
        R[t][0] = 0.f;
        for (int j = 0; j < 14; ++j){ run += fmS[t * 14 + j]; R[t][j + 1] = run; }
    }
    __syncthreads();
    if (t < 15){
        float run = 0.f;
        I[0][t] = 0.f;
        for (int i = 0; i < 14; ++i){ run += R[i][t]; I[i + 1][t] = run; }
    }
    __syncthreads();

    // ---- phase 3: 917 window scores ----
    if (t < NW){
        int r, i, j; decode_w(t, r, i, j);
        int rh = c_rh[r], rw = c_rw[r];
        float sum = I[i + rh][j + rw] - I[i][j + rw] - I[i + rh][j] + I[i][j];
        float sc = sum / (float)(rh * rw);
        s[t] = sc;
        out_scores[(size_t)b * NW + t] = sc;
    }
    __syncthreads();

    // ---- phase 4/5 overlap: wave 0 = NMS (no barriers); waves 1-15 = logits GEMV ----
    if (wv == 0){
        // per-lane window state, all statically indexed (full unroll)
        float sc_[15]; unsigned pk_[15]; int gr_[15];
        #pragma unroll
        for (int m = 0; m < 15; ++m){
            int w = lane + (m << 6);
            bool ok = w < NW;
            int r = 0, i = 0, j = 0;
            if (ok) decode_w(w, r, i, j);
            sc_[m] = ok ? s[w] : 0.f;
            pk_[m] = (unsigned)(i | (j << 4) | (c_rh[r] << 8) | (c_rw[r] << 12));
            gr_[m] = ok ? ((w >= 602) ? 2 : (w >= 361) ? 1 : 0) : 3;
        }
        unsigned vmask = 0x7FFFu;
        int slot = 0;
        #pragma unroll
        for (int g = 0; g < 3; ++g){
            int npick = (g == 0) ? 3 : (g == 1) ? 2 : 1;
            int last  = (g == 0) ? 0 : (g == 1) ? 361 : 602;
            for (int p = 0; p < npick; ++p){
                unsigned long long key = 0ULL;
                #pragma unroll
                for (int m = 0; m < 15; ++m){
                    if (gr_[m] == g && ((vmask >> m) & 1u)){
                        unsigned long long k2 = nms_key(sc_[m], lane + (m << 6));
                        if (k2 > key) key = k2;
                    }
                }
                #pragma unroll
                for (int off = 32; off > 0; off >>= 1){
                    unsigned long long o = shfl_xor_u64(key, off);
                    if (o > key) key = o;
                }
                int pick = (key == 0ULL) ? last
                                         : (int)(0xFFFFFFFFu - (unsigned)(key & 0xFFFFFFFFu));
                last = pick;
                int pr, pi, pj; decode_w(pick, pr, pi, pj);
                float px0 = pi * 32.f, py0 = pj * 32.f;
                float prh = (float)c_rh[pr], prw = (float)c_rw[pr];
                float px1 = px0 + prh * 32.f - 1.f, py1 = py0 + prw * 32.f - 1.f;
                float pa  = prh * prw * 1024.f;
                #pragma unroll
                for (int m = 0; m < 15; ++m){
                    if (gr_[m] == g && ((vmask >> m) & 1u)){
                        unsigned pk = pk_[m];
                        float x0 = (float)(pk & 15u) * 32.f;
                        float y0 = (float)((pk >> 4) & 15u) * 32.f;
                        float rh = (float)((pk >> 8) & 15u);
                        float rw = (float)(pk >> 12);
                        float x1 = x0 + rh * 32.f - 1.f;
                        float y1 = y0 + rw * 32.f - 1.f;
                        float ar = rh * rw * 1024.f;
                        float lx = fminf(x1, px1) - fmaxf(x0, px0) + 1.f;
                        float ly = fminf(y1, py1) - fmaxf(y0, py0) + 1.f;
                        float inter = (lx < 0.f || ly < 0.f) ? 0.f : lx * ly;
                        float iou = inter / (ar + pa - inter);
                        if (iou > 0.25f) vmask &= ~(1u << m);
                    }
                }
                if (lane == 0){
                    out_idx[b * 6 + slot] = (float)pick;
                    out_psc[b * 6 + slot] = s[pick];
                }
                slot++;
            }
        }
    } else {
        // logits GEMV: 16 lanes per row, 4 rows per wave, 15 waves, 4 passes
        int gw  = wv - 1;           // 0..14
        int grp = lane >> 4;        // 0..3
        int s16 = lane & 15;
        const float4* emb4 = (const float4*)emb;
        for (int p = 0; p < 4; ++p){
            int row = p * 60 + gw * 4 + grp;
            if (row < 200){
                const float4* wrow = (const float4*)(Wc + (size_t)row * 512);
                float acc = 0.f;
                #pragma unroll
                for (int k = 0; k < 8; ++k){
                    float4 w = wrow[k * 16 + s16];
                    float4 e = emb4[k * 16 + s16];
                    acc += e.x * w.x + e.y * w.y + e.z * w.z + e.w * w.w;
                }
                acc += __shfl_xor(acc, 1);
                acc += __shfl_xor(acc, 2);
                acc += __shfl_xor(acc, 4);
                acc += __shfl_xor(acc, 8);
                if (s16 == 0){
                    float v = acc + bc[row];
                    lg[row] = v;
                    out_logits[(size_t)b * 200 + row] = v;
                }
            }
        }
    }
    __syncthreads();

    // ---- phase 6: per-wave redundant argmax over lg[0..199] (no extra barrier) ----
    {
        unsigned long long key = nms_key(lg[lane], lane);
        unsigned long long k2  = nms_key(lg[lane + 64], lane + 64);
        if (k2 > key) key = k2;
        k2 = nms_key(lg[lane + 128], lane + 128);
        if (k2 > key) key = k2;
        if (lane + 192 < 200){
            k2 = nms_key(lg[lane + 192], lane + 192);
            if (k2 > key) key = k2;
        }
        #pragma unroll
        for (int off = 32; off > 0; off >>= 1){
            unsigned long long o = shfl_xor_u64(key, off);
            if (o > key) key = o;
        }
        int amax = (int)(0xFFFFFFFFu - (unsigned)(key & 0xFFFFFFFFu));
        if (t < 200) mk[t] = lg[t] * (t == amax ? 1.0f : 0.7f);
    }
    __syncthreads();

    // ---- phase 7: hash GEMV: 16 lanes per row, 48 rows in one pass ----
    if (t < 768){
        int row = t >> 4;
        int s16 = t & 15;
        const float4* wrow = (const float4*)(Wh + (size_t)row * 200);
        const float4* mk4  = (const float4*)mk;
        float4 w0 = wrow[s16],      m0 = mk4[s16];
        float4 w1 = wrow[s16 + 16], m1 = mk4[s16 + 16];
        float4 w2 = wrow[s16 + 32], m2 = mk4[s16 + 32];
        float acc = w0.x*m0.x + w0.y*m0.y + w0.z*m0.z + w0.w*m0.w
                  + w1.x*m1.x + w1.y*m1.y + w1.z*m1.z + w1.w*m1.w
                  + w2.x*m2.x + w2.y*m2.y + w2.z*m2.z + w2.w*m2.w;
        if (s16 < 2){
            float4 w3 = wrow[s16 + 48], m3 = mk4[s16 + 48];
            acc += w3.x*m3.x + w3.y*m3.y + w3.z*m3.z + w3.w*m3.w;
        }
        acc += __shfl_xor(acc, 1);
        acc += __shfl_xor(acc, 2);
        acc += __shfl_xor(acc, 4);
        acc += __shfl_xor(acc, 8);
        if (s16 == 0) out_hash[b * 48 + row] = tanhf(acc + bh[row]);
    }
}

extern "C" void kernel_launch(void* const* d_in, const int* in_sizes, int n_in,
                              void* d_out, int out_size, void* d_ws, size_t ws_size,
                              hipStream_t stream) {
    const float* fm = (const float*)d_in[0];
    const float* E  = (const float*)d_in[1];
    const float* Wc = (const float*)d_in[2];
    const float* bc = (const float*)d_in[3];
    const float* Wh = (const float*)d_in[4];
    const float* bh = (const float*)d_in[5];
    float* out        = (float*)d_out;
    float* out_hash   = out;                 // 256*48   = 12288
    float* out_logits = out + 12288;         // 256*200  = 51200
    float* out_idx    = out + 63488;         // 256*6    = 1536
    float* out_psc    = out + 65024;         // 256*6    = 1536
    float* out_scores = out + 66560;         // 256*917  = 234752

    hipLaunchKernelGGL(mono_kernel, dim3(256), dim3(1024), 0, stream,
                       fm, E, Wc, bc, Wh, bh,
                       out_hash, out_logits, out_idx, out_psc, out_scores);
}